// Round 9
// baseline (266.756 us; speedup 1.0000x reference)
//
#include <hip/hip_runtime.h>

// Backward warp, bilinear sampling. B=16, H=W=1024 (pow2, hardcoded), C=3, fp32.
// R9 = R5 (best: 141us) + ONE change: gather loads are nontemporal (L1 no-alloc).
// Probe to discriminate: (a) VMEM addr-rate-bound (neutral) vs (b) L1 fill/evict
// serialization from the ~76KB/CU live gather window thrashing 32KB L1 (-10-20%).
// Structure: 1 px/thread, 64x4 tile/block, tile_y-fastest + XCD-chunked swizzle,
// fused 24B row-pair gathers, scalar NT stores (exact-196MB writes per R5/R8 A/B).

typedef float f4u __attribute__((ext_vector_type(4), aligned(4)));
typedef float f2u __attribute__((ext_vector_type(2), aligned(4)));

__global__ __launch_bounds__(256) void backwarp_kernel(
    const float* __restrict__ image,
    const float* __restrict__ flow,
    float* __restrict__ out) {
  constexpr int H = 1024, W = 1024;
  constexpr int NB = 65536;        // 16 batches * 16 tile_x * 256 tile_y
  constexpr int CHUNK = NB / 8;

  // XCD-chunked swizzle (65536 % 8 == 0 -> bijective)
  int bid = blockIdx.x;
  int sb = (bid & 7) * CHUNK + (bid >> 3);

  // tile-column-major: consecutive sb -> vertically adjacent tiles
  int b      = sb >> 12;           // 4096 tiles per batch
  int r      = sb & 4095;
  int tile_x = r >> 8;             // [0,16)
  int tile_y = r & 255;            // [0,256)

  int lane = threadIdx.x & 63;
  int wrow = threadIdx.x >> 6;     // [0,4)

  int w = (tile_x << 6) + lane;
  int h = (tile_y << 2) + wrow;
  int idx = (b << 20) + (h << 10) + w;
  int plane = b << 20;

  float2 f = *reinterpret_cast<const float2*>(flow + (size_t)idx * 2);

  float x = (float)w + f.x;
  float y = (float)h + f.y;
  // faithful round-trip from the reference (x/1024 == x*(1/1024) exactly)
  x = 0.5f * (2.0f * (x * (1.0f / W) - 0.5f) + 1.0f) * W;
  y = 0.5f * (2.0f * (y * (1.0f / H) - 0.5f) + 1.0f) * H;

  int x0 = (int)x;                 // trunc toward zero, like astype(int32)
  int y0 = (int)y;
  int x1 = x0 + 1;
  int y1 = y0 + 1;
  x0 = min(max(x0, 0), W - 1);
  x1 = min(max(x1, 0), W - 1);
  y0 = min(max(y0, 0), H - 1);
  y1 = min(max(y1, 0), H - 1);

  float wa = ((float)x1 - x) * ((float)y1 - y);
  float wb = ((float)x1 - x) * (y - (float)y0);
  float wc = (x - (float)x0) * ((float)y1 - y);
  float wd = (x - (float)x0) * (y - (float)y0);

  // Fused gather: 6 contiguous floats starting at bx cover pixels {bx, bx+1};
  // select halves for (x0, x1) including all border-clamp cases.
  int bx = min(x0, W - 2);         // keep the 6-float load in-bounds of the row
  bool hiA = (x0 != bx);           // pa lives in floats [3..5]
  bool hiC = (x1 != bx);

  const float* row0 = image + (size_t)(plane + (y0 << 10) + bx) * 3;
  const float* row1 = image + (size_t)(plane + (y1 << 10) + bx) * 3;
  f4u r0a = __builtin_nontemporal_load(reinterpret_cast<const f4u*>(row0));
  f2u r0b = __builtin_nontemporal_load(reinterpret_cast<const f2u*>(row0 + 4));
  f4u r1a = __builtin_nontemporal_load(reinterpret_cast<const f4u*>(row1));
  f2u r1b = __builtin_nontemporal_load(reinterpret_cast<const f2u*>(row1 + 4));
  float a[6] = {r0a.x, r0a.y, r0a.z, r0a.w, r0b.x, r0b.y};
  float c[6] = {r1a.x, r1a.y, r1a.z, r1a.w, r1b.x, r1b.y};

  float* o = out + (size_t)idx * 3;
#pragma unroll
  for (int ch = 0; ch < 3; ++ch) {
    float pa  = hiA ? a[3 + ch] : a[ch];
    float pc_ = hiC ? a[3 + ch] : a[ch];
    float pb  = hiA ? c[3 + ch] : c[ch];
    float pd  = hiC ? c[3 + ch] : c[ch];
    __builtin_nontemporal_store(wa * pa + wb * pb + wc * pc_ + wd * pd, o + ch);
  }
}

extern "C" void kernel_launch(void* const* d_in, const int* in_sizes, int n_in,
                              void* d_out, int out_size, void* d_ws, size_t ws_size,
                              hipStream_t stream) {
  const float* image = (const float*)d_in[0];
  const float* flow  = (const float*)d_in[1];
  float* out = (float*)d_out;

  backwarp_kernel<<<65536, 256, 0, stream>>>(image, flow, out);
}

// Round 10
// 137.580 us; speedup vs baseline: 1.9389x; 1.9389x over previous
//
#include <hip/hip_runtime.h>

// Backward warp, bilinear sampling. B=16, H=W=1024 (pow2, hardcoded), C=3, fp32.
// FINAL (R5 revert — best of R1..R9 at 140.9us):
//   - 1 px/thread, block = 64w x 4h tile (wave = one 64-px row slice)
//   - tile-column-major block order + XCD-chunked swizzle (vertical L2 reuse)
//   - fused 24B row-pair gathers (cached: R9 proved L1/L2 absorb ~40% of
//     gather traffic; NT bypass cost 2x)
//   - nontemporal scalar stores (exact 196MB writes; wider NT stores amplify)
// Plateau ~5.1 cy/px on the scattered-gather tag/line-service path; MLP x4,
// instr-count x3, LDS staging, and cache-policy probes all neutral-to-negative.

struct __attribute__((packed, aligned(4))) R6 { float v[6]; };

__global__ __launch_bounds__(256) void backwarp_kernel(
    const float* __restrict__ image,
    const float* __restrict__ flow,
    float* __restrict__ out) {
  constexpr int H = 1024, W = 1024;
  constexpr int NB = 65536;        // 16 batches * 16 tile_x * 256 tile_y
  constexpr int CHUNK = NB / 8;

  // XCD-chunked swizzle (65536 % 8 == 0 -> bijective)
  int bid = blockIdx.x;
  int sb = (bid & 7) * CHUNK + (bid >> 3);

  // tile-column-major: consecutive sb -> vertically adjacent tiles
  int b      = sb >> 12;           // 4096 tiles per batch
  int r      = sb & 4095;
  int tile_x = r >> 8;             // [0,16)
  int tile_y = r & 255;            // [0,256)

  int lane = threadIdx.x & 63;
  int wrow = threadIdx.x >> 6;     // [0,4)

  int w = (tile_x << 6) + lane;
  int h = (tile_y << 2) + wrow;
  int idx = (b << 20) + (h << 10) + w;
  int plane = b << 20;

  float2 f = *reinterpret_cast<const float2*>(flow + (size_t)idx * 2);

  float x = (float)w + f.x;
  float y = (float)h + f.y;
  // faithful round-trip from the reference (x/1024 == x*(1/1024) exactly)
  x = 0.5f * (2.0f * (x * (1.0f / W) - 0.5f) + 1.0f) * W;
  y = 0.5f * (2.0f * (y * (1.0f / H) - 0.5f) + 1.0f) * H;

  int x0 = (int)x;                 // trunc toward zero, like astype(int32)
  int y0 = (int)y;
  int x1 = x0 + 1;
  int y1 = y0 + 1;
  x0 = min(max(x0, 0), W - 1);
  x1 = min(max(x1, 0), W - 1);
  y0 = min(max(y0, 0), H - 1);
  y1 = min(max(y1, 0), H - 1);

  float wa = ((float)x1 - x) * ((float)y1 - y);
  float wb = ((float)x1 - x) * (y - (float)y0);
  float wc = (x - (float)x0) * ((float)y1 - y);
  float wd = (x - (float)x0) * (y - (float)y0);

  // Fused gather: 6 contiguous floats starting at bx cover pixels {bx, bx+1};
  // select halves for (x0, x1) including all border-clamp cases.
  int bx = min(x0, W - 2);         // keep the 6-float load in-bounds of the row
  bool hiA = (x0 != bx);           // pa lives in v[3..5]
  bool hiC = (x1 != bx);           // pc lives in v[3..5]

  const R6 r0 = *reinterpret_cast<const R6*>(image + (size_t)(plane + (y0 << 10) + bx) * 3);
  const R6 r1 = *reinterpret_cast<const R6*>(image + (size_t)(plane + (y1 << 10) + bx) * 3);

  float* o = out + (size_t)idx * 3;
#pragma unroll
  for (int c = 0; c < 3; ++c) {
    float pa  = hiA ? r0.v[3 + c] : r0.v[c];
    float pc_ = hiC ? r0.v[3 + c] : r0.v[c];
    float pb  = hiA ? r1.v[3 + c] : r1.v[c];
    float pd  = hiC ? r1.v[3 + c] : r1.v[c];
    __builtin_nontemporal_store(wa * pa + wb * pb + wc * pc_ + wd * pd, o + c);
  }
}

extern "C" void kernel_launch(void* const* d_in, const int* in_sizes, int n_in,
                              void* d_out, int out_size, void* d_ws, size_t ws_size,
                              hipStream_t stream) {
  const float* image = (const float*)d_in[0];
  const float* flow  = (const float*)d_in[1];
  float* out = (float*)d_out;

  backwarp_kernel<<<65536, 256, 0, stream>>>(image, flow, out);
}